// Round 17
// baseline (1038.102 us; speedup 1.0000x reference)
//
#include <hip/hip_runtime.h>
#include <cstdint>
#include <cstddef>

// Problem constants (match reference)
#define P_NODES 100000
#define A_NODES 50000
#define IN_CH   128
#define H_CH    256
#define OUT_CH  349
#define NE_W    600000
#define NE_C    1000000

#define SCAN_BS 512

typedef unsigned short u16;
typedef unsigned int   u32;
typedef __bf16 bf16x8 __attribute__((ext_vector_type(8)));
typedef float  f32x4  __attribute__((ext_vector_type(4)));
typedef u16    u16x4  __attribute__((ext_vector_type(4)));
typedef u16    u16x8  __attribute__((ext_vector_type(8)));

// fp32 -> bf16 round-to-nearest-even
__device__ __forceinline__ u16 f2bf(float f) {
    u32 u = __builtin_bit_cast(u32, f);
    u += 0x7FFFu + ((u >> 16) & 1u);
    return (u16)(u >> 16);
}
__device__ __forceinline__ float bf2f(u16 v) {
    return __builtin_bit_cast(float, (u32)v << 16);
}

// async global->LDS, 16 B per lane. LDS dest is wave-uniform base + lane*16.
typedef const __attribute__((address_space(1))) u32 gas_u32;
typedef __attribute__((address_space(3))) u32 las_u32;
__device__ __forceinline__ void gl_lds16(const void* g, void* l)
{
    __builtin_amdgcn_global_load_lds(
        reinterpret_cast<gas_u32*>(reinterpret_cast<uintptr_t>(g)),
        reinterpret_cast<las_u32*>(reinterpret_cast<uintptr_t>(l)),
        16, 0, 0);
}

// ---------------------------------------------------------------------------
// MFMA bf16 GEMM, C[M,N] = A[M,K] @ W[K,N] + bias. Tile 128x128, BK=64,
// 512 thr = 8 waves (verified R14: occupancy 26->51%, 124->104us).
//
// R14 change: tile-level DOUBLE-BUFFERED prefetch. R14 counters: MfmaUtil
// only 23%, HBM 34%, occ 51% -> staging latency still serially exposed
// (stage -> full-drain barrier -> compute every K-step). Now: issue next
// tile's gl_lds16 into buf^1 BEFORE computing buf; the end-of-step
// __syncthreads (implicit vmcnt(0)) then waits on loads issued a full
// compute phase (128 MFMAs) earlier -> flight hidden. Barriers 2->1/K-step.
// Race-free: buf^1 was last read before the PREVIOUS barrier.
// LDS 64KB -> still 2 blocks/CU (occupancy unchanged).
//
// Wave grid 4Mx2N, each wave 32x64 out, acc[2][4]=32 VGPR. Staging: wave w
// covers rows [w*16,w*16+16) per 32-wide K-chunk; lane l -> LDS byte
// w*1024 + l*16 (linear, matches DMA).
//
// 1-D super-tile remap (verified R8: FETCH 234->83MB): the ntb N-blocks of
// the same M-panel sit exactly 8 apart in dispatch order -> same XCD ->
// A-panel re-reads hit that XCD's 4MB L2. Correctness independent of mapping.
//
// LDS unpadded (row = 32 u16 = 64 B) with XOR swizzle chunk ^= (row>>1)&3
// applied on the global-address side so fragment ds_read_b128s are 2-way
// (free).
// ---------------------------------------------------------------------------
template<bool OUTBF, bool RELU>
__global__ __launch_bounds__(512) void mfma_gemm(
    const u16* __restrict__ A, int lda,
    const u16* __restrict__ WT, int ldw,
    const float* __restrict__ bias, void* __restrict__ Cv, int ldc,
    int M, int N, int K)
{
    __shared__ u16 Asl[2][2][128 * 32];   // [tile-buf][k-chunk]
    __shared__ u16 Bsl[2][2][128 * 32];

    // ---- super-tile block remap (same-M N-blocks 8 apart -> same XCD) ----
    const int mt_blocks = (M + 127) >> 7;
    const int ntb = (N + 127) >> 7;
    const int bid  = blockIdx.x;
    const int grp  = bid / (8 * ntb);
    const int rr   = bid - grp * (8 * ntb);
    const int mtile = grp * 8 + (rr & 7);
    const int nidx  = rr >> 3;
    if (mtile >= mt_blocks) return;
    const int blockM = mtile * 128;
    const int blockN = nidx * 128;

    const int tid = threadIdx.x;
    const int w    = tid >> 6;          // 0..7
    const int lane = tid & 63;
    const int m16  = lane & 15;
    const int quad = lane >> 4;
    const int wr   = (w >> 1) * 32;     // 4 M-rows of waves, 32 rows each
    const int wc   = (w & 1) * 64;      // 2 N-cols of waves, 64 cols each

    // ragged blocks: pre-zero LDS; masked DMA lanes never overwrite -> zeros
    if (blockM + 128 > M || blockN + 128 > N) {
        u16* az = &Asl[0][0][0]; u16* bz = &Bsl[0][0][0];
        for (int i = tid; i < 2 * 2 * 128 * 32; i += 512) { az[i] = 0; bz[i] = 0; }
    }
    __syncthreads();

    // staging: wave w covers tile rows [w*16, w*16+16) (one gl_lds16/chunk)
    const int ra  = lane >> 2;               // 0..15 row within wave's stripe
    const int rA  = w * 16 + ra;             // tile row
    const int cs  = ((lane & 3) ^ ((rA >> 1) & 3)) * 8;  // swizzled k-offset (u16)

    const u16* gA = A  + (size_t)(blockM + rA) * lda + cs;
    const u16* gB = WT + (size_t)(blockN + rA) * ldw + cs;
    const bool vA = blockM + rA < M;
    const bool vB = blockN + rA < N;
    const int lofs = (w * 16) * 32;

    auto stage = [&](int buf, int k0) {
        if (vA) { gl_lds16(gA + k0,      &Asl[buf][0][lofs]);
                  gl_lds16(gA + k0 + 32, &Asl[buf][1][lofs]); }
        if (vB) { gl_lds16(gB + k0,      &Bsl[buf][0][lofs]);
                  gl_lds16(gB + k0 + 32, &Bsl[buf][1][lofs]); }
    };

    // fragment read swizzle (row-in-tile = 16*t + m16 -> s = (m16>>1)&3)
    const int swz = (quad ^ ((m16 >> 1) & 3)) * 8;

    f32x4 acc[2][4];
#pragma unroll
    for (int i = 0; i < 2; ++i)
#pragma unroll
        for (int j = 0; j < 4; ++j) acc[i][j] = (f32x4){0.f, 0.f, 0.f, 0.f};

    // prologue: stage tile 0; barrier makes it visible (implicit vmcnt(0))
    stage(0, 0);
    __syncthreads();

    int cur = 0;
    for (int k0 = 0; k0 < K; k0 += 64) {
        // issue next tile's loads BEFORE computing current (overlap)
        if (k0 + 64 < K) stage(cur ^ 1, k0 + 64);

#pragma unroll
        for (int kk = 0; kk < 2; ++kk) {
            bf16x8 af[2], bfr[4];
#pragma unroll
            for (int mt = 0; mt < 2; ++mt)
                af[mt] = *(const bf16x8*)&Asl[cur][kk][(wr + mt * 16 + m16) * 32 + swz];
#pragma unroll
            for (int nt = 0; nt < 4; ++nt)
                bfr[nt] = *(const bf16x8*)&Bsl[cur][kk][(wc + nt * 16 + m16) * 32 + swz];
#pragma unroll
            for (int mt = 0; mt < 2; ++mt)
#pragma unroll
                for (int nt = 0; nt < 4; ++nt)
                    acc[mt][nt] = __builtin_amdgcn_mfma_f32_16x16x32_bf16(
                        af[mt], bfr[nt], acc[mt][nt], 0, 0, 0);
        }
        // single barrier: drains next-tile DMA (vmcnt) + everyone done
        // reading cur -> safe to overwrite next iteration
        __syncthreads();
        cur ^= 1;
    }

    // epilogue: C/D layout col=lane&15, row=quad*4+reg
#pragma unroll
    for (int mt = 0; mt < 2; ++mt) {
#pragma unroll
        for (int nt = 0; nt < 4; ++nt) {
            int col = blockN + wc + nt * 16 + m16;
            if (col >= N) continue;
#pragma unroll
            for (int reg = 0; reg < 4; ++reg) {
                int row = blockM + wr + mt * 16 + quad * 4 + reg;
                if (row >= M) continue;
                float v = acc[mt][nt][reg];
                if (bias) v += bias[col];
                if constexpr (RELU) v = fmaxf(v, 0.f);
                size_t off = (size_t)row * ldc + col;
                if constexpr (OUTBF) ((u16*)Cv)[off] = f2bf(v);
                else                 ((float*)Cv)[off] = v;
            }
        }
    }
}

// host-side grid size for the super-tile remap
static inline int gemm_grid(int M, int N)
{
    int mt = (M + 127) / 128;
    int ntb = (N + 127) / 128;
    return ((mt + 7) / 8) * 8 * ntb;
}

// ---------------------------------------------------------------------------
// Fused input converts: x_paper -> bf16 [P,128]; emb -> bf16 [A,512-stride]
// ---------------------------------------------------------------------------
__global__ void prep_convert(const float* __restrict__ x, u16* __restrict__ x_bf,
                             const float* __restrict__ emb, u16* __restrict__ emb_bf)
{
    int i = blockIdx.x * blockDim.x + threadIdx.x;
    const int NX = P_NODES * IN_CH / 4;
    const int NE = A_NODES * H_CH / 4;
    if (i < NX) {
        float4 v = *(const float4*)(x + (size_t)i * 4);
        u16x4 o = {f2bf(v.x), f2bf(v.y), f2bf(v.z), f2bf(v.w)};
        *(u16x4*)(x_bf + (size_t)i * 4) = o;
    } else if (i < NX + NE) {
        int j = i - NX;
        int r = j >> 6, c = (j & 63) * 4;
        float4 v = *(const float4*)(emb + (size_t)r * H_CH + c);
        u16x4 o = {f2bf(v.x), f2bf(v.y), f2bf(v.z), f2bf(v.w)};
        *(u16x4*)(emb_bf + (size_t)r * 512 + c) = o;
    }
}

// ---------------------------------------------------------------------------
// All 9 weight transposes (fp32 W[K,N] -> bf16 WT[n*ldk + koff + k]) fused.
// ---------------------------------------------------------------------------
__global__ void transpose_all(
    const float* __restrict__ lin, const float* __restrict__ r0p,
    const float* __restrict__ c0wr, const float* __restrict__ c0ci,
    const float* __restrict__ r0a, const float* __restrict__ c0rv,
    const float* __restrict__ r1, const float* __restrict__ c1wr,
    const float* __restrict__ c1ci,
    u16* __restrict__ wt_lin, u16* __restrict__ wt_l0p,
    u16* __restrict__ wt_l0a, u16* __restrict__ wt_l1)
{
    int i = blockIdx.x * blockDim.x + threadIdx.x;
    const float* W; u16* WT; int N, ldk, koff;
    if (i < 32768)       { W = lin;  WT = wt_lin; N = 256; ldk = 128; koff = 0;   }
    else if (i < 98304)  { i -= 32768;  W = r0p;  WT = wt_l0p; N = 256; ldk = 768; koff = 0;   }
    else if (i < 163840) { i -= 98304;  W = c0wr; WT = wt_l0p; N = 256; ldk = 768; koff = 256; }
    else if (i < 229376) { i -= 163840; W = c0ci; WT = wt_l0p; N = 256; ldk = 768; koff = 512; }
    else if (i < 294912) { i -= 229376; W = r0a;  WT = wt_l0a; N = 256; ldk = 512; koff = 0;   }
    else if (i < 360448) { i -= 294912; W = c0rv; WT = wt_l0a; N = 256; ldk = 512; koff = 256; }
    else if (i < 449792) { i -= 360448; W = r1;   WT = wt_l1;  N = 349; ldk = 768; koff = 0;   }
    else if (i < 539136) { i -= 449792; W = c1wr; WT = wt_l1;  N = 349; ldk = 768; koff = 256; }
    else if (i < 628480) { i -= 539136; W = c1ci; WT = wt_l1;  N = 349; ldk = 768; koff = 512; }
    else return;
    int k = i / N, n = i - k * N;
    WT[(size_t)n * ldk + koff + k] = f2bf(W[(size_t)k * N + n]);
}

// ---------------------------------------------------------------------------
// CSR construction (3 graphs fused per phase)
// ---------------------------------------------------------------------------
__global__ void deg3_kernel(const int* __restrict__ wd, const int* __restrict__ cd,
                            const int* __restrict__ rd,
                            int* __restrict__ deg_w, int* __restrict__ deg_c,
                            int* __restrict__ deg_r)
{
    int e = blockIdx.x * blockDim.x + threadIdx.x;
    if (e < NE_W) atomicAdd(&deg_w[wd[e]], 1);
    if (e < NE_C) atomicAdd(&deg_c[cd[e]], 1);
    if (e < NE_W) atomicAdd(&deg_r[rd[e]], 1);
}

__global__ __launch_bounds__(SCAN_BS) void scan_a3(
    const int* __restrict__ dw, const int* __restrict__ dc, const int* __restrict__ dr,
    int* __restrict__ pw, int* __restrict__ pc, int* __restrict__ pr, int* __restrict__ blk)
{
    __shared__ int s[SCAN_BS];
    int g = blockIdx.y;
    const int* deg = (g == 0) ? dw : (g == 1) ? dc : dr;
    int* ptr = (g == 0) ? pw : (g == 1) ? pc : pr;
    int n = (g == 2) ? A_NODES : P_NODES;
    int tid = threadIdx.x;
    int i = blockIdx.x * SCAN_BS + tid;
    int v = (i < n) ? deg[i] : 0;
    s[tid] = v;
    __syncthreads();
    for (int off = 1; off < SCAN_BS; off <<= 1) {
        int t = 0;
        if (tid >= off) t = s[tid - off];
        __syncthreads();
        s[tid] += t;
        __syncthreads();
    }
    if (i < n) ptr[i] = s[tid] - v;
    if (tid == SCAN_BS - 1) blk[g * 256 + blockIdx.x] = s[tid];
}

__global__ __launch_bounds__(SCAN_BS) void scan_b3(int* __restrict__ blk)
{
    __shared__ int s[SCAN_BS];
    int g = blockIdx.x;
    int tid = threadIdx.x;
    int v = (tid < 256) ? blk[g * 256 + tid] : 0;
    s[tid] = v;
    __syncthreads();
    for (int off = 1; off < SCAN_BS; off <<= 1) {
        int t = 0;
        if (tid >= off) t = s[tid - off];
        __syncthreads();
        s[tid] += t;
        __syncthreads();
    }
    if (tid < 256) blk[g * 256 + tid] = s[tid] - v;
}

__global__ void scan_c3(const int* __restrict__ dw, const int* __restrict__ dc,
                        const int* __restrict__ dr,
                        int* __restrict__ pw, int* __restrict__ pc, int* __restrict__ pr,
                        const int* __restrict__ blk,
                        int* __restrict__ cw, int* __restrict__ cc, int* __restrict__ cr,
                        float* __restrict__ iw, float* __restrict__ ic, float* __restrict__ ir)
{
    int g = blockIdx.y;
    const int* deg = (g == 0) ? dw : (g == 1) ? dc : dr;
    int* ptr = (g == 0) ? pw : (g == 1) ? pc : pr;
    int* cur = (g == 0) ? cw : (g == 1) ? cc : cr;
    float* inv = (g == 0) ? iw : (g == 1) ? ic : ir;
    int n = (g == 2) ? A_NODES : P_NODES;
    int E = (g == 1) ? NE_C : NE_W;
    int i = blockIdx.x * blockDim.x + threadIdx.x;
    if (i < n) {
        int p = ptr[i] + blk[g * 256 + i / SCAN_BS];
        ptr[i] = p;
        cur[i] = p;
        inv[i] = 1.0f / fmaxf((float)deg[i], 1.0f);
    }
    if (i == 0) ptr[n] = E;
}

// ---------------------------------------------------------------------------
// CSR fill, XCD-partitioned by dst range (R0 win: WRITE_SIZE 143MB -> slab-
// local writes coalesce in per-XCD L2; fill3 dropped out of the top-5).
// ---------------------------------------------------------------------------
__global__ __launch_bounds__(256) void fill3_kernel(
    const int* __restrict__ wsrc, const int* __restrict__ wdst,
    const int* __restrict__ csrc, const int* __restrict__ cdst,
    const int* __restrict__ rsrc, const int* __restrict__ rdst,
    int* __restrict__ cw, int* __restrict__ cc, int* __restrict__ cr,
    int* __restrict__ iw, int* __restrict__ ic, int* __restrict__ ir)
{
    const int g   = blockIdx.x & 7;                    // presumed XCD id
    const int bi  = blockIdx.x >> 3;                   // block index within group
    const int nbt = (gridDim.x >> 3) * blockDim.x;     // threads per group
    const int t0  = bi * blockDim.x + threadIdx.x;

    const int plo = g * (P_NODES / 8), phi = plo + P_NODES / 8;  // 12500 nodes
    const int alo = g * (A_NODES / 8), ahi = alo + A_NODES / 8;  // 6250 nodes

    for (int e = t0; e < NE_W; e += nbt) {
        int d = wdst[e];
        if (d >= plo && d < phi) { int p = atomicAdd(&cw[d], 1); iw[p] = wsrc[e]; }
    }
    for (int e = t0; e < NE_C; e += nbt) {
        int d = cdst[e];
        if (d >= plo && d < phi) { int p = atomicAdd(&cc[d], 1); ic[p] = csrc[e]; }
    }
    for (int e = t0; e < NE_W; e += nbt) {
        int d = rdst[e];
        if (d >= alo && d < ahi) { int p = atomicAdd(&cr[d], 1); ir[p] = rsrc[e]; }
    }
}

// ---------------------------------------------------------------------------
// Gather aggregation, D=256 bf16. Half-wave (32 lanes x 16B) per dst row,
// 4-edge unroll (8 row-loads in flight per wave).
// ---------------------------------------------------------------------------
__global__ __launch_bounds__(256) void gather_bf16(
    const u16* __restrict__ T, int ldt,
    const int* __restrict__ ptr, const int* __restrict__ idx,
    const float* __restrict__ inv, u16* __restrict__ out, int ldo, int R)
{
    int row = blockIdx.x * 8 + (threadIdx.x >> 5);
    if (row >= R) return;
    int l = (threadIdx.x & 31) * 8;
    int s = ptr[row], e = ptr[row + 1];
    float acc[8];
#pragma unroll
    for (int q = 0; q < 8; ++q) acc[q] = 0.f;
    int j = s;
    for (; j + 3 < e; j += 4) {
        int i0 = idx[j], i1 = idx[j + 1], i2 = idx[j + 2], i3 = idx[j + 3];
        u16x8 t0 = *(const u16x8*)(T + (size_t)i0 * ldt + l);
        u16x8 t1 = *(const u16x8*)(T + (size_t)i1 * ldt + l);
        u16x8 t2 = *(const u16x8*)(T + (size_t)i2 * ldt + l);
        u16x8 t3 = *(const u16x8*)(T + (size_t)i3 * ldt + l);
#pragma unroll
        for (int q = 0; q < 8; ++q)
            acc[q] += (bf2f(t0[q]) + bf2f(t1[q])) + (bf2f(t2[q]) + bf2f(t3[q]));
    }
    for (; j < e; ++j) {
        int i0 = idx[j];
        u16x8 t0 = *(const u16x8*)(T + (size_t)i0 * ldt + l);
#pragma unroll
        for (int q = 0; q < 8; ++q) acc[q] += bf2f(t0[q]);
    }
    float wgt = inv[row];
    u16x8 o;
#pragma unroll
    for (int q = 0; q < 8; ++q) o[q] = f2bf(acc[q] * wgt);
    *(u16x8*)(out + (size_t)row * ldo + l) = o;
}

// In-place per-row log_softmax, one wave per row, register-resident
__global__ __launch_bounds__(64) void log_softmax_kernel(float* __restrict__ x)
{
    const int row = blockIdx.x;
    const int lane = threadIdx.x;
    float* xr = x + (size_t)row * OUT_CH;

    float v[6];
    float m = -3.402823466e38f;
#pragma unroll
    for (int o = 0; o < 6; ++o) {
        int j = lane + o * 64;
        v[o] = (j < OUT_CH) ? xr[j] : -3.402823466e38f;
        m = fmaxf(m, v[o]);
    }
#pragma unroll
    for (int off = 32; off > 0; off >>= 1) m = fmaxf(m, __shfl_xor(m, off));

    float s = 0.f;
#pragma unroll
    for (int o = 0; o < 6; ++o) {
        int j = lane + o * 64;
        if (j < OUT_CH) s += __expf(v[o] - m);
    }
#pragma unroll
    for (int off = 32; off > 0; off >>= 1) s += __shfl_xor(s, off);

    float lse = m + __logf(s);
#pragma unroll
    for (int o = 0; o < 6; ++o) {
        int j = lane + o * 64;
        if (j < OUT_CH) xr[j] = v[o] - lse;
    }
}

// ---------------------------------------------------------------------------
extern "C" void kernel_launch(void* const* d_in, const int* in_sizes, int n_in,
                              void* d_out, int out_size, void* d_ws, size_t ws_size,
                              hipStream_t stream)
{
    const float* x_paper = (const float*)d_in[0];
    const float* emb_a   = (const float*)d_in[1];
    const float* lin_w   = (const float*)d_in[2];
    const float* lin_b   = (const float*)d_in[3];
    const float* r0p_w   = (const float*)d_in[4];
    const float* r0p_b   = (const float*)d_in[5];
    const float* r0a_w   = (const float*)d_in[6];
    const float* r0a_b   = (const float*)d_in[7];
    const float* c0_wr   = (const float*)d_in[8];
    const float* c0_ci   = (const float*)d_in[9];
    const float* c0_rv   = (const float*)d_in[10];
    const float* r1_w    = (const float*)d_in[11];
    const float* r1_b    = (const float*)d_in[12];
    const float* c1_wr   = (const float*)d_in[13];
    const float* c1_ci   = (const float*)d_in[14];
    const int*   w_src   = (const int*)d_in[15];
    const int*   w_dst   = (const int*)d_in[16];
    const int*   c_src   = (const int*)d_in[17];
    const int*   c_dst   = (const int*)d_in[18];
    const int*   r_src   = (const int*)d_in[19];
    const int*   r_dst   = (const int*)d_in[20];

    // ---------------- workspace layout (d_ws) ----------------
    const size_t P768 = (size_t)P_NODES * 768;

    u16* big_A0 = (u16*)d_ws;              // P x 768: [h_p | agg_w0 | agg_c0]
    u16* big_A1 = big_A0 + P768;           // P x 768: [relu_p | agg_w1 | agg_c1]
    u16* x_bf   = big_A1 + P768;           // P x 128
    u16* wt_lin = x_bf + (size_t)P_NODES * IN_CH;   // 256 x 128
    u16* wt_l0p = wt_lin + 32768;          // 256 x 768
    u16* wt_l0a = wt_l0p + 196608;         // 256 x 512
    u16* wt_l1  = wt_l0a + 131072;         // 349 x 768
    float* inv_w = (float*)(wt_l1 + 268032 + 64);
    float* inv_c = inv_w + P_NODES;
    float* inv_r = inv_c + P_NODES;

    int* ip    = (int*)(inv_r + A_NODES);
    int* deg_w = ip;                 ip += P_NODES;
    int* deg_c = ip;                 ip += P_NODES;
    int* deg_r = ip;                 ip += A_NODES;
    int* ptr_w = ip;                 ip += P_NODES + 1;
    int* ptr_c = ip;                 ip += P_NODES + 1;
    int* ptr_r = ip;                 ip += A_NODES + 1;
    int* cur_w = ip;                 ip += P_NODES;
    int* cur_c = ip;                 ip += P_NODES;
    int* cur_r = ip;                 ip += A_NODES;
    int* idx_w = ip;                 ip += NE_W;
    int* idx_c = ip;                 ip += NE_C;
    int* idx_r = ip;                 ip += NE_W;
    int* blk   = ip;                 ip += 3 * 256;

    // ---------------- d_out-resident scratch (dead before final GEMM) ------
    u16* big_A0a  = (u16*)d_out;                         // A x 512: [emb_bf | agg_r0]
    u16* out_a_bf = big_A0a + (size_t)A_NODES * 512;     // A x 256
    float* logits = (float*)d_out;                       // P x 349 (final)

    // ---------------- prep: converts + weight transposes ----------------
    {
        int n = P_NODES * IN_CH / 4 + A_NODES * H_CH / 4;
        prep_convert<<<(n + 255) / 256, 256, 0, stream>>>(x_paper, x_bf, emb_a, big_A0a);
    }
    transpose_all<<<(628480 + 255) / 256, 256, 0, stream>>>(
        lin_w, r0p_w, c0_wr, c0_ci, r0a_w, c0_rv, r1_w, c1_wr, c1_ci,
        wt_lin, wt_l0p, wt_l0a, wt_l1);

    // ---------------- CSR builds ----------------
    hipMemsetAsync(deg_w, 0, (size_t)(2 * P_NODES + A_NODES) * sizeof(int), stream);
    deg3_kernel<<<(NE_C + 255) / 256, 256, 0, stream>>>(w_dst, c_dst, r_dst, deg_w, deg_c, deg_r);
    {
        dim3 ga((P_NODES + SCAN_BS - 1) / SCAN_BS, 3);
        scan_a3<<<ga, SCAN_BS, 0, stream>>>(deg_w, deg_c, deg_r, ptr_w, ptr_c, ptr_r, blk);
        scan_b3<<<3, SCAN_BS, 0, stream>>>(blk);
        dim3 gc((P_NODES + 255) / 256, 3);
        scan_c3<<<gc, 256, 0, stream>>>(deg_w, deg_c, deg_r, ptr_w, ptr_c, ptr_r, blk,
                                        cur_w, cur_c, cur_r, inv_w, inv_c, inv_r);
    }
    // 2048 blocks = 8 dst-range groups x 256 blocks; full occupancy (8 wg/CU)
    fill3_kernel<<<2048, 256, 0, stream>>>(
        w_src, w_dst, c_src, c_dst, r_src, r_dst, cur_w, cur_c, cur_r, idx_w, idx_c, idx_r);

    // ---------------- fused pipeline ----------------
    auto gat = [&](const u16* T, int ldt, const int* ptr, const int* idx,
                   const float* inv, u16* out, int ldo, int R) {
        gather_bf16<<<(R + 7) / 8, 256, 0, stream>>>(T, ldt, ptr, idx, inv, out, ldo, R);
    };

    // h_p = x @ lin_w + b -> big_A0 cols [0:256)
    mfma_gemm<true, false><<<gemm_grid(P_NODES, 256), 512, 0, stream>>>(
        x_bf, IN_CH, wt_lin, 128, lin_b, big_A0, 768, P_NODES, H_CH, IN_CH);

    gat(big_A0a, 512, ptr_w, idx_w, inv_w, big_A0 + 256, 768, P_NODES);   // agg_w0 = mean_w(emb)
    gat(big_A0, 768, ptr_c, idx_c, inv_c, big_A0 + 512, 768, P_NODES);    // agg_c0 = mean_c(h_p)
    gat(big_A0, 768, ptr_r, idx_r, inv_r, big_A0a + 256, 512, A_NODES);   // agg_r0 = mean_r(h_p)

    // relu_p = relu(big_A0 @ [r0p; c0wr; c0ci] + b) -> big_A1 cols [0:256)
    mfma_gemm<true, true><<<gemm_grid(P_NODES, 256), 512, 0, stream>>>(
        big_A0, 768, wt_l0p, 768, r0p_b, big_A1, 768, P_NODES, H_CH, 768);

    // relu_a = relu(big_A0a @ [r0a; c0rv] + b) -> out_a_bf
    mfma_gemm<true, true><<<gemm_grid(A_NODES, 256), 512, 0, stream>>>(
        big_A0a, 512, wt_l0a, 512, r0a_b, out_a_bf, 256, A_NODES, H_CH, 512);

    gat(out_a_bf, 256, ptr_w, idx_w, inv_w, big_A1 + 256, 768, P_NODES);  // agg_w1
    gat(big_A1, 768, ptr_c, idx_c, inv_c, big_A1 + 512, 768, P_NODES);    // agg_c1

    // logits = big_A1 @ [r1; c1wr; c1ci] + b (fp32, overwrites d_out scratch)
    mfma_gemm<false, false><<<gemm_grid(P_NODES, OUT_CH), 512, 0, stream>>>(
        big_A1, 768, wt_l1, 768, r1_b, logits, OUT_CH, P_NODES, OUT_CH, 768);

    // ---------------- log_softmax in place ----------------
    log_softmax_kernel<<<P_NODES, 64, 0, stream>>>(logits);
}

// Round 21
// 1022.756 us; speedup vs baseline: 1.0150x; 1.0150x over previous
//
#include <hip/hip_runtime.h>
#include <cstdint>
#include <cstddef>

// Problem constants (match reference)
#define P_NODES 100000
#define A_NODES 50000
#define IN_CH   128
#define H_CH    256
#define OUT_CH  349
#define NE_W    600000
#define NE_C    1000000

#define SCAN_BS 512

typedef unsigned short u16;
typedef unsigned int   u32;
typedef __bf16 bf16x8 __attribute__((ext_vector_type(8)));
typedef float  f32x4  __attribute__((ext_vector_type(4)));
typedef u16    u16x4  __attribute__((ext_vector_type(4)));
typedef u16    u16x8  __attribute__((ext_vector_type(8)));

// fp32 -> bf16 round-to-nearest-even
__device__ __forceinline__ u16 f2bf(float f) {
    u32 u = __builtin_bit_cast(u32, f);
    u += 0x7FFFu + ((u >> 16) & 1u);
    return (u16)(u >> 16);
}
__device__ __forceinline__ float bf2f(u16 v) {
    return __builtin_bit_cast(float, (u32)v << 16);
}

// async global->LDS, 16 B per lane. LDS dest is wave-uniform base + lane*16.
typedef const __attribute__((address_space(1))) u32 gas_u32;
typedef __attribute__((address_space(3))) u32 las_u32;
__device__ __forceinline__ void gl_lds16(const void* g, void* l)
{
    __builtin_amdgcn_global_load_lds(
        reinterpret_cast<gas_u32*>(reinterpret_cast<uintptr_t>(g)),
        reinterpret_cast<las_u32*>(reinterpret_cast<uintptr_t>(l)),
        16, 0, 0);
}

// ---------------------------------------------------------------------------
// MFMA bf16 GEMM, C[M,N] = A[M,K] @ W[K,N] + bias. Tile 128x128, BK=64,
// 512 thr = 8 waves. EXACT R14 version (verified: occ 51%, final GEMM
// 104us, end-to-end 1026us).
//
// R17 post-mortem: tile-level double-buffer (64KB LDS) REGRESSED 104->117us
// (occ 51->33%, VGPR 36->52) -> reverted. The single-buffer 32KB structure
// is the best measured; GEMM arc closed (142->104us over R5-R14).
//
// Wave grid 4Mx2N, each wave 32x64 out, acc[2][4]=32 VGPR. Staging: wave w
// covers rows [w*16,w*16+16) per 32-wide K-chunk; lane l -> LDS byte
// w*1024 + l*16 (linear, matches DMA).
//
// 1-D super-tile remap (verified R8: FETCH 234->83MB): the ntb N-blocks of
// the same M-panel sit exactly 8 apart in dispatch order -> same XCD ->
// A-panel re-reads hit that XCD's 4MB L2. Correctness independent of mapping.
//
// LDS unpadded (row = 32 u16 = 64 B) with XOR swizzle chunk ^= (row>>1)&3
// applied on the global-address side so fragment ds_read_b128s are 2-way
// (free).
// ---------------------------------------------------------------------------
template<bool OUTBF, bool RELU>
__global__ __launch_bounds__(512) void mfma_gemm(
    const u16* __restrict__ A, int lda,
    const u16* __restrict__ WT, int ldw,
    const float* __restrict__ bias, void* __restrict__ Cv, int ldc,
    int M, int N, int K)
{
    __shared__ u16 Asl[2][128 * 32];
    __shared__ u16 Bsl[2][128 * 32];

    // ---- super-tile block remap (same-M N-blocks 8 apart -> same XCD) ----
    const int mt_blocks = (M + 127) >> 7;
    const int ntb = (N + 127) >> 7;
    const int bid  = blockIdx.x;
    const int grp  = bid / (8 * ntb);
    const int rr   = bid - grp * (8 * ntb);
    const int mtile = grp * 8 + (rr & 7);
    const int nidx  = rr >> 3;
    if (mtile >= mt_blocks) return;
    const int blockM = mtile * 128;
    const int blockN = nidx * 128;

    const int tid = threadIdx.x;
    const int w    = tid >> 6;          // 0..7
    const int lane = tid & 63;
    const int m16  = lane & 15;
    const int quad = lane >> 4;
    const int wr   = (w >> 1) * 32;     // 4 M-rows of waves, 32 rows each
    const int wc   = (w & 1) * 64;      // 2 N-cols of waves, 64 cols each

    // ragged blocks: pre-zero LDS; masked DMA lanes never overwrite -> zeros
    if (blockM + 128 > M || blockN + 128 > N) {
        u16* az = &Asl[0][0]; u16* bz = &Bsl[0][0];
        for (int i = tid; i < 2 * 128 * 32; i += 512) { az[i] = 0; bz[i] = 0; }
    }
    __syncthreads();

    // staging: wave w covers tile rows [w*16, w*16+16) (one gl_lds16/chunk)
    const int ra  = lane >> 2;               // 0..15 row within wave's stripe
    const int rA  = w * 16 + ra;             // tile row
    const int cs  = ((lane & 3) ^ ((rA >> 1) & 3)) * 8;  // swizzled k-offset (u16)

    const u16* gA = A  + (size_t)(blockM + rA) * lda + cs;
    const u16* gB = WT + (size_t)(blockN + rA) * ldw + cs;
    u16* lA[2] = { &Asl[0][(w * 16) * 32], &Asl[1][(w * 16) * 32] };
    u16* lB[2] = { &Bsl[0][(w * 16) * 32], &Bsl[1][(w * 16) * 32] };
    const bool vA = blockM + rA < M;
    const bool vB = blockN + rA < N;

    // fragment read swizzle (row-in-tile = 16*t + m16 -> s = (m16>>1)&3)
    const int swz = (quad ^ ((m16 >> 1) & 3)) * 8;

    f32x4 acc[2][4];
#pragma unroll
    for (int i = 0; i < 2; ++i)
#pragma unroll
        for (int j = 0; j < 4; ++j) acc[i][j] = (f32x4){0.f, 0.f, 0.f, 0.f};

    for (int k0 = 0; k0 < K; k0 += 64) {
        // stage BOTH 32-wide K-chunks, then one barrier pair for the MFMAs
        if (vA) { gl_lds16(gA + k0, lA[0]); gl_lds16(gA + k0 + 32, lA[1]); }
        if (vB) { gl_lds16(gB + k0, lB[0]); gl_lds16(gB + k0 + 32, lB[1]); }
        __syncthreads();

#pragma unroll
        for (int kk = 0; kk < 2; ++kk) {
            bf16x8 af[2], bfr[4];
#pragma unroll
            for (int mt = 0; mt < 2; ++mt)
                af[mt] = *(const bf16x8*)&Asl[kk][(wr + mt * 16 + m16) * 32 + swz];
#pragma unroll
            for (int nt = 0; nt < 4; ++nt)
                bfr[nt] = *(const bf16x8*)&Bsl[kk][(wc + nt * 16 + m16) * 32 + swz];
#pragma unroll
            for (int mt = 0; mt < 2; ++mt)
#pragma unroll
                for (int nt = 0; nt < 4; ++nt)
                    acc[mt][nt] = __builtin_amdgcn_mfma_f32_16x16x32_bf16(
                        af[mt], bfr[nt], acc[mt][nt], 0, 0, 0);
        }
        __syncthreads();
    }

    // epilogue: C/D layout col=lane&15, row=quad*4+reg
#pragma unroll
    for (int mt = 0; mt < 2; ++mt) {
#pragma unroll
        for (int nt = 0; nt < 4; ++nt) {
            int col = blockN + wc + nt * 16 + m16;
            if (col >= N) continue;
#pragma unroll
            for (int reg = 0; reg < 4; ++reg) {
                int row = blockM + wr + mt * 16 + quad * 4 + reg;
                if (row >= M) continue;
                float v = acc[mt][nt][reg];
                if (bias) v += bias[col];
                if constexpr (RELU) v = fmaxf(v, 0.f);
                size_t off = (size_t)row * ldc + col;
                if constexpr (OUTBF) ((u16*)Cv)[off] = f2bf(v);
                else                 ((float*)Cv)[off] = v;
            }
        }
    }
}

// host-side grid size for the super-tile remap
static inline int gemm_grid(int M, int N)
{
    int mt = (M + 127) / 128;
    int ntb = (N + 127) / 128;
    return ((mt + 7) / 8) * 8 * ntb;
}

// ---------------------------------------------------------------------------
// Fused input converts: x_paper -> bf16 [P,128]; emb -> bf16 [A,512-stride]
// ---------------------------------------------------------------------------
__global__ void prep_convert(const float* __restrict__ x, u16* __restrict__ x_bf,
                             const float* __restrict__ emb, u16* __restrict__ emb_bf)
{
    int i = blockIdx.x * blockDim.x + threadIdx.x;
    const int NX = P_NODES * IN_CH / 4;
    const int NE = A_NODES * H_CH / 4;
    if (i < NX) {
        float4 v = *(const float4*)(x + (size_t)i * 4);
        u16x4 o = {f2bf(v.x), f2bf(v.y), f2bf(v.z), f2bf(v.w)};
        *(u16x4*)(x_bf + (size_t)i * 4) = o;
    } else if (i < NX + NE) {
        int j = i - NX;
        int r = j >> 6, c = (j & 63) * 4;
        float4 v = *(const float4*)(emb + (size_t)r * H_CH + c);
        u16x4 o = {f2bf(v.x), f2bf(v.y), f2bf(v.z), f2bf(v.w)};
        *(u16x4*)(emb_bf + (size_t)r * 512 + c) = o;
    }
}

// ---------------------------------------------------------------------------
// All 9 weight transposes (fp32 W[K,N] -> bf16 WT[n*ldk + koff + k]) fused.
// ---------------------------------------------------------------------------
__global__ void transpose_all(
    const float* __restrict__ lin, const float* __restrict__ r0p,
    const float* __restrict__ c0wr, const float* __restrict__ c0ci,
    const float* __restrict__ r0a, const float* __restrict__ c0rv,
    const float* __restrict__ r1, const float* __restrict__ c1wr,
    const float* __restrict__ c1ci,
    u16* __restrict__ wt_lin, u16* __restrict__ wt_l0p,
    u16* __restrict__ wt_l0a, u16* __restrict__ wt_l1)
{
    int i = blockIdx.x * blockDim.x + threadIdx.x;
    const float* W; u16* WT; int N, ldk, koff;
    if (i < 32768)       { W = lin;  WT = wt_lin; N = 256; ldk = 128; koff = 0;   }
    else if (i < 98304)  { i -= 32768;  W = r0p;  WT = wt_l0p; N = 256; ldk = 768; koff = 0;   }
    else if (i < 163840) { i -= 98304;  W = c0wr; WT = wt_l0p; N = 256; ldk = 768; koff = 256; }
    else if (i < 229376) { i -= 163840; W = c0ci; WT = wt_l0p; N = 256; ldk = 768; koff = 512; }
    else if (i < 294912) { i -= 229376; W = r0a;  WT = wt_l0a; N = 256; ldk = 512; koff = 0;   }
    else if (i < 360448) { i -= 294912; W = c0rv; WT = wt_l0a; N = 256; ldk = 512; koff = 256; }
    else if (i < 449792) { i -= 360448; W = r1;   WT = wt_l1;  N = 349; ldk = 768; koff = 0;   }
    else if (i < 539136) { i -= 449792; W = c1wr; WT = wt_l1;  N = 349; ldk = 768; koff = 256; }
    else if (i < 628480) { i -= 539136; W = c1ci; WT = wt_l1;  N = 349; ldk = 768; koff = 512; }
    else return;
    int k = i / N, n = i - k * N;
    WT[(size_t)n * ldk + koff + k] = f2bf(W[(size_t)k * N + n]);
}

// ---------------------------------------------------------------------------
// CSR construction (3 graphs fused per phase)
// ---------------------------------------------------------------------------
__global__ void deg3_kernel(const int* __restrict__ wd, const int* __restrict__ cd,
                            const int* __restrict__ rd,
                            int* __restrict__ deg_w, int* __restrict__ deg_c,
                            int* __restrict__ deg_r)
{
    int e = blockIdx.x * blockDim.x + threadIdx.x;
    if (e < NE_W) atomicAdd(&deg_w[wd[e]], 1);
    if (e < NE_C) atomicAdd(&deg_c[cd[e]], 1);
    if (e < NE_W) atomicAdd(&deg_r[rd[e]], 1);
}

__global__ __launch_bounds__(SCAN_BS) void scan_a3(
    const int* __restrict__ dw, const int* __restrict__ dc, const int* __restrict__ dr,
    int* __restrict__ pw, int* __restrict__ pc, int* __restrict__ pr, int* __restrict__ blk)
{
    __shared__ int s[SCAN_BS];
    int g = blockIdx.y;
    const int* deg = (g == 0) ? dw : (g == 1) ? dc : dr;
    int* ptr = (g == 0) ? pw : (g == 1) ? pc : pr;
    int n = (g == 2) ? A_NODES : P_NODES;
    int tid = threadIdx.x;
    int i = blockIdx.x * SCAN_BS + tid;
    int v = (i < n) ? deg[i] : 0;
    s[tid] = v;
    __syncthreads();
    for (int off = 1; off < SCAN_BS; off <<= 1) {
        int t = 0;
        if (tid >= off) t = s[tid - off];
        __syncthreads();
        s[tid] += t;
        __syncthreads();
    }
    if (i < n) ptr[i] = s[tid] - v;
    if (tid == SCAN_BS - 1) blk[g * 256 + blockIdx.x] = s[tid];
}

__global__ __launch_bounds__(SCAN_BS) void scan_b3(int* __restrict__ blk)
{
    __shared__ int s[SCAN_BS];
    int g = blockIdx.x;
    int tid = threadIdx.x;
    int v = (tid < 256) ? blk[g * 256 + tid] : 0;
    s[tid] = v;
    __syncthreads();
    for (int off = 1; off < SCAN_BS; off <<= 1) {
        int t = 0;
        if (tid >= off) t = s[tid - off];
        __syncthreads();
        s[tid] += t;
        __syncthreads();
    }
    if (tid < 256) blk[g * 256 + tid] = s[tid] - v;
}

__global__ void scan_c3(const int* __restrict__ dw, const int* __restrict__ dc,
                        const int* __restrict__ dr,
                        int* __restrict__ pw, int* __restrict__ pc, int* __restrict__ pr,
                        const int* __restrict__ blk,
                        int* __restrict__ cw, int* __restrict__ cc, int* __restrict__ cr,
                        float* __restrict__ iw, float* __restrict__ ic, float* __restrict__ ir)
{
    int g = blockIdx.y;
    const int* deg = (g == 0) ? dw : (g == 1) ? dc : dr;
    int* ptr = (g == 0) ? pw : (g == 1) ? pc : pr;
    int* cur = (g == 0) ? cw : (g == 1) ? cc : cr;
    float* inv = (g == 0) ? iw : (g == 1) ? ic : ir;
    int n = (g == 2) ? A_NODES : P_NODES;
    int E = (g == 1) ? NE_C : NE_W;
    int i = blockIdx.x * blockDim.x + threadIdx.x;
    if (i < n) {
        int p = ptr[i] + blk[g * 256 + i / SCAN_BS];
        ptr[i] = p;
        cur[i] = p;
        inv[i] = 1.0f / fmaxf((float)deg[i], 1.0f);
    }
    if (i == 0) ptr[n] = E;
}

// ---------------------------------------------------------------------------
// CSR fill, XCD-partitioned by dst range (R0 win: WRITE_SIZE 143MB -> slab-
// local writes coalesce in per-XCD L2; fill3 dropped out of the top-5).
// ---------------------------------------------------------------------------
__global__ __launch_bounds__(256) void fill3_kernel(
    const int* __restrict__ wsrc, const int* __restrict__ wdst,
    const int* __restrict__ csrc, const int* __restrict__ cdst,
    const int* __restrict__ rsrc, const int* __restrict__ rdst,
    int* __restrict__ cw, int* __restrict__ cc, int* __restrict__ cr,
    int* __restrict__ iw, int* __restrict__ ic, int* __restrict__ ir)
{
    const int g   = blockIdx.x & 7;                    // presumed XCD id
    const int bi  = blockIdx.x >> 3;                   // block index within group
    const int nbt = (gridDim.x >> 3) * blockDim.x;     // threads per group
    const int t0  = bi * blockDim.x + threadIdx.x;

    const int plo = g * (P_NODES / 8), phi = plo + P_NODES / 8;  // 12500 nodes
    const int alo = g * (A_NODES / 8), ahi = alo + A_NODES / 8;  // 6250 nodes

    for (int e = t0; e < NE_W; e += nbt) {
        int d = wdst[e];
        if (d >= plo && d < phi) { int p = atomicAdd(&cw[d], 1); iw[p] = wsrc[e]; }
    }
    for (int e = t0; e < NE_C; e += nbt) {
        int d = cdst[e];
        if (d >= plo && d < phi) { int p = atomicAdd(&cc[d], 1); ic[p] = csrc[e]; }
    }
    for (int e = t0; e < NE_W; e += nbt) {
        int d = rdst[e];
        if (d >= alo && d < ahi) { int p = atomicAdd(&cr[d], 1); ir[p] = rsrc[e]; }
    }
}

// ---------------------------------------------------------------------------
// Gather aggregation, D=256 bf16. R17 change: QUARTER-wave (16 lanes) per
// dst row, each lane covers 16 cols via two contiguous 256B segments
// (bytes [0,256) and [256,512) of the row). Doubles rows in flight per
// wave (MLP 8->16 row-loads) and rows per block (8->16) vs half-wave.
// 4-edge unroll retained.
// ---------------------------------------------------------------------------
__global__ __launch_bounds__(256) void gather_bf16(
    const u16* __restrict__ T, int ldt,
    const int* __restrict__ ptr, const int* __restrict__ idx,
    const float* __restrict__ inv, u16* __restrict__ out, int ldo, int R)
{
    int row = blockIdx.x * 16 + (threadIdx.x >> 4);
    if (row >= R) return;
    int l0 = (threadIdx.x & 15) * 8;        // u16 offset in [0,128)
    int l1 = 128 + l0;                      // u16 offset in [128,256)
    int s = ptr[row], e = ptr[row + 1];
    float acc[16];
#pragma unroll
    for (int q = 0; q < 16; ++q) acc[q] = 0.f;
    int j = s;
    for (; j + 3 < e; j += 4) {
        int i0 = idx[j], i1 = idx[j + 1], i2 = idx[j + 2], i3 = idx[j + 3];
        const u16* r0 = T + (size_t)i0 * ldt;
        const u16* r1 = T + (size_t)i1 * ldt;
        const u16* r2 = T + (size_t)i2 * ldt;
        const u16* r3 = T + (size_t)i3 * ldt;
        u16x8 a0 = *(const u16x8*)(r0 + l0), b0 = *(const u16x8*)(r0 + l1);
        u16x8 a1 = *(const u16x8*)(r1 + l0), b1 = *(const u16x8*)(r1 + l1);
        u16x8 a2 = *(const u16x8*)(r2 + l0), b2 = *(const u16x8*)(r2 + l1);
        u16x8 a3 = *(const u16x8*)(r3 + l0), b3 = *(const u16x8*)(r3 + l1);
#pragma unroll
        for (int q = 0; q < 8; ++q) {
            acc[q]     += (bf2f(a0[q]) + bf2f(a1[q])) + (bf2f(a2[q]) + bf2f(a3[q]));
            acc[q + 8] += (bf2f(b0[q]) + bf2f(b1[q])) + (bf2f(b2[q]) + bf2f(b3[q]));
        }
    }
    for (; j < e; ++j) {
        const u16* r0 = T + (size_t)idx[j] * ldt;
        u16x8 a0 = *(const u16x8*)(r0 + l0), b0 = *(const u16x8*)(r0 + l1);
#pragma unroll
        for (int q = 0; q < 8; ++q) {
            acc[q]     += bf2f(a0[q]);
            acc[q + 8] += bf2f(b0[q]);
        }
    }
    float wgt = inv[row];
    u16x8 o0, o1;
#pragma unroll
    for (int q = 0; q < 8; ++q) {
        o0[q] = f2bf(acc[q] * wgt);
        o1[q] = f2bf(acc[q + 8] * wgt);
    }
    *(u16x8*)(out + (size_t)row * ldo + l0) = o0;
    *(u16x8*)(out + (size_t)row * ldo + l1) = o1;
}

// In-place per-row log_softmax, one wave per row, register-resident
__global__ __launch_bounds__(64) void log_softmax_kernel(float* __restrict__ x)
{
    const int row = blockIdx.x;
    const int lane = threadIdx.x;
    float* xr = x + (size_t)row * OUT_CH;

    float v[6];
    float m = -3.402823466e38f;
#pragma unroll
    for (int o = 0; o < 6; ++o) {
        int j = lane + o * 64;
        v[o] = (j < OUT_CH) ? xr[j] : -3.402823466e38f;
        m = fmaxf(m, v[o]);
    }
#pragma unroll
    for (int off = 32; off > 0; off >>= 1) m = fmaxf(m, __shfl_xor(m, off));

    float s = 0.f;
#pragma unroll
    for (int o = 0; o < 6; ++o) {
        int j = lane + o * 64;
        if (j < OUT_CH) s += __expf(v[o] - m);
    }
#pragma unroll
    for (int off = 32; off > 0; off >>= 1) s += __shfl_xor(s, off);

    float lse = m + __logf(s);
#pragma unroll
    for (int o = 0; o < 6; ++o) {
        int j = lane + o * 64;
        if (j < OUT_CH) xr[j] = v[o] - lse;
    }
}

// ---------------------------------------------------------------------------
extern "C" void kernel_launch(void* const* d_in, const int* in_sizes, int n_in,
                              void* d_out, int out_size, void* d_ws, size_t ws_size,
                              hipStream_t stream)
{
    const float* x_paper = (const float*)d_in[0];
    const float* emb_a   = (const float*)d_in[1];
    const float* lin_w   = (const float*)d_in[2];
    const float* lin_b   = (const float*)d_in[3];
    const float* r0p_w   = (const float*)d_in[4];
    const float* r0p_b   = (const float*)d_in[5];
    const float* r0a_w   = (const float*)d_in[6];
    const float* r0a_b   = (const float*)d_in[7];
    const float* c0_wr   = (const float*)d_in[8];
    const float* c0_ci   = (const float*)d_in[9];
    const float* c0_rv   = (const float*)d_in[10];
    const float* r1_w    = (const float*)d_in[11];
    const float* r1_b    = (const float*)d_in[12];
    const float* c1_wr   = (const float*)d_in[13];
    const float* c1_ci   = (const float*)d_in[14];
    const int*   w_src   = (const int*)d_in[15];
    const int*   w_dst   = (const int*)d_in[16];
    const int*   c_src   = (const int*)d_in[17];
    const int*   c_dst   = (const int*)d_in[18];
    const int*   r_src   = (const int*)d_in[19];
    const int*   r_dst   = (const int*)d_in[20];

    // ---------------- workspace layout (d_ws) ----------------
    const size_t P768 = (size_t)P_NODES * 768;

    u16* big_A0 = (u16*)d_ws;              // P x 768: [h_p | agg_w0 | agg_c0]
    u16* big_A1 = big_A0 + P768;           // P x 768: [relu_p | agg_w1 | agg_c1]
    u16* x_bf   = big_A1 + P768;           // P x 128
    u16* wt_lin = x_bf + (size_t)P_NODES * IN_CH;   // 256 x 128
    u16* wt_l0p = wt_lin + 32768;          // 256 x 768
    u16* wt_l0a = wt_l0p + 196608;         // 256 x 512
    u16* wt_l1  = wt_l0a + 131072;         // 349 x 768
    float* inv_w = (float*)(wt_l1 + 268032 + 64);
    float* inv_c = inv_w + P_NODES;
    float* inv_r = inv_c + P_NODES;

    int* ip    = (int*)(inv_r + A_NODES);
    int* deg_w = ip;                 ip += P_NODES;
    int* deg_c = ip;                 ip += P_NODES;
    int* deg_r = ip;                 ip += A_NODES;
    int* ptr_w = ip;                 ip += P_NODES + 1;
    int* ptr_c = ip;                 ip += P_NODES + 1;
    int* ptr_r = ip;                 ip += A_NODES + 1;
    int* cur_w = ip;                 ip += P_NODES;
    int* cur_c = ip;                 ip += P_NODES;
    int* cur_r = ip;                 ip += A_NODES;
    int* idx_w = ip;                 ip += NE_W;
    int* idx_c = ip;                 ip += NE_C;
    int* idx_r = ip;                 ip += NE_W;
    int* blk   = ip;                 ip += 3 * 256;

    // ---------------- d_out-resident scratch (dead before final GEMM) ------
    u16* big_A0a  = (u16*)d_out;                         // A x 512: [emb_bf | agg_r0]
    u16* out_a_bf = big_A0a + (size_t)A_NODES * 512;     // A x 256
    float* logits = (float*)d_out;                       // P x 349 (final)

    // ---------------- prep: converts + weight transposes ----------------
    {
        int n = P_NODES * IN_CH / 4 + A_NODES * H_CH / 4;
        prep_convert<<<(n + 255) / 256, 256, 0, stream>>>(x_paper, x_bf, emb_a, big_A0a);
    }
    transpose_all<<<(628480 + 255) / 256, 256, 0, stream>>>(
        lin_w, r0p_w, c0_wr, c0_ci, r0a_w, c0_rv, r1_w, c1_wr, c1_ci,
        wt_lin, wt_l0p, wt_l0a, wt_l1);

    // ---------------- CSR builds ----------------
    hipMemsetAsync(deg_w, 0, (size_t)(2 * P_NODES + A_NODES) * sizeof(int), stream);
    deg3_kernel<<<(NE_C + 255) / 256, 256, 0, stream>>>(w_dst, c_dst, r_dst, deg_w, deg_c, deg_r);
    {
        dim3 ga((P_NODES + SCAN_BS - 1) / SCAN_BS, 3);
        scan_a3<<<ga, SCAN_BS, 0, stream>>>(deg_w, deg_c, deg_r, ptr_w, ptr_c, ptr_r, blk);
        scan_b3<<<3, SCAN_BS, 0, stream>>>(blk);
        dim3 gc((P_NODES + 255) / 256, 3);
        scan_c3<<<gc, 256, 0, stream>>>(deg_w, deg_c, deg_r, ptr_w, ptr_c, ptr_r, blk,
                                        cur_w, cur_c, cur_r, inv_w, inv_c, inv_r);
    }
    // 2048 blocks = 8 dst-range groups x 256 blocks; full occupancy (8 wg/CU)
    fill3_kernel<<<2048, 256, 0, stream>>>(
        w_src, w_dst, c_src, c_dst, r_src, r_dst, cur_w, cur_c, cur_r, idx_w, idx_c, idx_r);

    // ---------------- fused pipeline ----------------
    auto gat = [&](const u16* T, int ldt, const int* ptr, const int* idx,
                   const float* inv, u16* out, int ldo, int R) {
        gather_bf16<<<(R + 15) / 16, 256, 0, stream>>>(T, ldt, ptr, idx, inv, out, ldo, R);
    };

    // h_p = x @ lin_w + b -> big_A0 cols [0:256)
    mfma_gemm<true, false><<<gemm_grid(P_NODES, 256), 512, 0, stream>>>(
        x_bf, IN_CH, wt_lin, 128, lin_b, big_A0, 768, P_NODES, H_CH, IN_CH);

    gat(big_A0a, 512, ptr_w, idx_w, inv_w, big_A0 + 256, 768, P_NODES);   // agg_w0 = mean_w(emb)
    gat(big_A0, 768, ptr_c, idx_c, inv_c, big_A0 + 512, 768, P_NODES);    // agg_c0 = mean_c(h_p)
    gat(big_A0, 768, ptr_r, idx_r, inv_r, big_A0a + 256, 512, A_NODES);   // agg_r0 = mean_r(h_p)

    // relu_p = relu(big_A0 @ [r0p; c0wr; c0ci] + b) -> big_A1 cols [0:256)
    mfma_gemm<true, true><<<gemm_grid(P_NODES, 256), 512, 0, stream>>>(
        big_A0, 768, wt_l0p, 768, r0p_b, big_A1, 768, P_NODES, H_CH, 768);

    // relu_a = relu(big_A0a @ [r0a; c0rv] + b) -> out_a_bf
    mfma_gemm<true, true><<<gemm_grid(A_NODES, 256), 512, 0, stream>>>(
        big_A0a, 512, wt_l0a, 512, r0a_b, out_a_bf, 256, A_NODES, H_CH, 512);

    gat(out_a_bf, 256, ptr_w, idx_w, inv_w, big_A1 + 256, 768, P_NODES);  // agg_w1
    gat(big_A1, 768, ptr_c, idx_c, inv_c, big_A1 + 512, 768, P_NODES);    // agg_c1

    // logits = big_A1 @ [r1; c1wr; c1ci] + b (fp32, overwrites d_out scratch)
    mfma_gemm<false, false><<<gemm_grid(P_NODES, OUT_CH), 512, 0, stream>>>(
        big_A1, 768, wt_l1, 768, r1_b, logits, OUT_CH, P_NODES, OUT_CH, 768);

    // ---------------- log_softmax in place ----------------
    log_softmax_kernel<<<P_NODES, 64, 0, stream>>>(logits);
}